// Round 6
// baseline (1069.311 us; speedup 1.0000x reference)
//
#include <hip/hip_runtime.h>
#include <hip/hip_fp16.h>

// Problem constants (fixed by the reference file)
#define M_DIM 16384   // B*S = 4*4096
#define N_DIM 4096    // DOUT
#define K_DIM 4096    // DIN

typedef __attribute__((ext_vector_type(16))) float f32x16;
typedef __attribute__((ext_vector_type(4)))  int   i32x4;
typedef __attribute__((ext_vector_type(8)))  int   i32x8;

// ---------------------------------------------------------------------------
// Quantize fp32 (fp16-exact values) -> fp8 RNE, emitting the 32x32x64 MFMA
// fragment-order tiled layout for 256-row blocks (UNCHANGED, verified r3-r5):
//   out = [nrow/256][K/64] tiles of 16384 B.
//   tile byte p = sb*2048 + half*1024 + l*16 + b   (sb 0..7, half 0..1,
//   l 0..63, b 0..15) holds element
//     row = tile_r*256 + sb*32 + (l&31)
//     k   = tile_k*64  + (l>>5)*32 + half*16 + b
//   so GEMM lane l reads its v_mfma_f32_32x32x64_f8f6f4 fragment as two
//   contiguous ds_read_b128 (base, base+1024) -> 0 bank conflicts; staging
//   is linear (global_load_lds-compatible).
// E4M3=true -> OCP e4m3fn (weight); false -> OCP e5m2 (activations).
// ---------------------------------------------------------------------------
template<bool E4M3>
__global__ __launch_bounds__(256) void quant_tile_kernel(
    const float* __restrict__ in,   // [R, K_DIM] row-major f32
    uint4* __restrict__ out,        // tiled fp8 bytes, R*K_DIM/16 groups
    int ngrp)
{
  int t = blockIdx.x * 256 + threadIdx.x;
  if (t >= ngrp) return;
  const int g    = t & 1023;        // 16-byte group within 16 KiB tile
  const int tile = t >> 10;
  const int kt   = tile & 63;       // K/64 = 64 K-tiles
  const int bt   = tile >> 6;       // 256-row block
  const int sb   = g >> 7;          // 32-row sub-block (0..7)
  const int half = (g >> 6) & 1;
  const int l    = g & 63;
  const int row  = bt * 256 + sb * 32 + (l & 31);
  const int k    = kt * 64 + (l >> 5) * 32 + half * 16;

  const float4* p = reinterpret_cast<const float4*>(in + (size_t)row * K_DIM + k);
  float4 v0 = p[0], v1 = p[1], v2 = p[2], v3 = p[3];
  int w0 = 0, w1 = 0, w2 = 0, w3 = 0;
  if (E4M3) {
    w0 = __builtin_amdgcn_cvt_pk_fp8_f32(v0.x, v0.y, w0, false);
    w0 = __builtin_amdgcn_cvt_pk_fp8_f32(v0.z, v0.w, w0, true);
    w1 = __builtin_amdgcn_cvt_pk_fp8_f32(v1.x, v1.y, w1, false);
    w1 = __builtin_amdgcn_cvt_pk_fp8_f32(v1.z, v1.w, w1, true);
    w2 = __builtin_amdgcn_cvt_pk_fp8_f32(v2.x, v2.y, w2, false);
    w2 = __builtin_amdgcn_cvt_pk_fp8_f32(v2.z, v2.w, w2, true);
    w3 = __builtin_amdgcn_cvt_pk_fp8_f32(v3.x, v3.y, w3, false);
    w3 = __builtin_amdgcn_cvt_pk_fp8_f32(v3.z, v3.w, w3, true);
  } else {
    w0 = __builtin_amdgcn_cvt_pk_bf8_f32(v0.x, v0.y, w0, false);
    w0 = __builtin_amdgcn_cvt_pk_bf8_f32(v0.z, v0.w, w0, true);
    w1 = __builtin_amdgcn_cvt_pk_bf8_f32(v1.x, v1.y, w1, false);
    w1 = __builtin_amdgcn_cvt_pk_bf8_f32(v1.z, v1.w, w1, true);
    w2 = __builtin_amdgcn_cvt_pk_bf8_f32(v2.x, v2.y, w2, false);
    w2 = __builtin_amdgcn_cvt_pk_bf8_f32(v2.z, v2.w, w2, true);
    w3 = __builtin_amdgcn_cvt_pk_bf8_f32(v3.x, v3.y, w3, false);
    w3 = __builtin_amdgcn_cvt_pk_bf8_f32(v3.z, v3.w, w3, true);
  }
  out[t] = make_uint4((unsigned)w0, (unsigned)w1, (unsigned)w2, (unsigned)w3);
}

// ---------------------------------------------------------------------------
// MX-fp8 GEMM, fat-wave regime: 256x256 block tile, BK=64, 4 waves (2Mx2N),
// per-wave 128x128 output = acc[4][4] f32x16 (256 regs) at 1 wave/SIMD
// (full 512-reg budget; __launch_bounds__(256,1)).
// Per K-tile: STAGE(kt+2, 8 loads) ; vmcnt(8)+barrier ; issue 16 ds_read_b128
// for tile kt+1 (i32x4 halves) ; 16 MFMA on tile kt's frags overlapping the
// LDS service ; lgkmcnt(0)+barrier. MFMA window/SIMD ~2190 cy doubles over
// the 8-wave variant while CU-level frag traffic drops to 64 KiB/K-tile.
// ---------------------------------------------------------------------------
__global__ __launch_bounds__(256, 1) void gemm_fp8_kernel(
    const unsigned char* __restrict__ Aq,   // tiled [64][64][16384] e5m2
    const unsigned char* __restrict__ Wq,   // tiled [16][64][16384] e4m3
    const float* __restrict__ bias,         // [N] fp16-exact values in f32
    float* __restrict__ C)                  // [M,N] f32 (fp16-rounded values)
{
  __shared__ __align__(16) unsigned char lds[65536];  // buf0|buf1, each {A 16K, B 16K}

  const int tid  = threadIdx.x;
  const int lane = tid & 63;
  const int wave = tid >> 6;                // 0..3
  const int wr   = wave >> 1;               // 0..1 -> 128 rows
  const int wc   = wave & 1;                // 0..1 -> 128 cols

  // T1: XCD swizzle (nwg=1024, %8==0). XCD x gets bni in {2x,2x+1}:
  // B panels L2-resident per XCD; A panels stream through LLC (A = 64 MiB total).
  const int bid = blockIdx.x;
  const int swz = (bid & 7) * 128 + (bid >> 3);
  const int bni = swz >> 6;                 // 0..15
  const int bmi = swz & 63;                 // 0..63

  const unsigned char* tA = Aq + (size_t)bmi * (64 * 16384);
  const unsigned char* tB = Wq + (size_t)bni * (64 * 16384);

  const size_t t16 = (size_t)tid * 16;      // per-lane global offset
  const int    w1k = wave * 1024;           // wave-uniform LDS offset

#define STAGE(gb, lo_)                                                      \
  __builtin_amdgcn_global_load_lds(                                        \
      (const __attribute__((address_space(1))) void*)((gb) + t16),          \
      (__attribute__((address_space(3))) void*)(lds + (lo_) + w1k), 16, 0, 0)

  // Stage one K-tile (A 16 KiB + B 16 KiB) into LDS buffer at `ldsbase`.
#define STAGE_TILE(tp, ldsbase)                                             \
  STAGE(tA + (tp),         (ldsbase) + 0);                                  \
  STAGE(tA + (tp) + 4096,  (ldsbase) + 4096);                               \
  STAGE(tA + (tp) + 8192,  (ldsbase) + 8192);                               \
  STAGE(tA + (tp) + 12288, (ldsbase) + 12288);                              \
  STAGE(tB + (tp),         (ldsbase) + 16384);                              \
  STAGE(tB + (tp) + 4096,  (ldsbase) + 20480);                              \
  STAGE(tB + (tp) + 8192,  (ldsbase) + 24576);                              \
  STAGE(tB + (tp) + 12288, (ldsbase) + 28672)

  // One fragment = two contiguous b128 reads (base, base+1024); halves kept
  // as i32x4 and joined at the MFMA call (regalloc can coalesce to 0 movs).
#define RD(lo_, hi_, off)                                                   \
  { const unsigned char* _p = lds + (off) + lane * 16;                      \
    lo_ = *(const i32x4*)_p; hi_ = *(const i32x4*)(_p + 1024); }

#define J(l_, h_) __builtin_shufflevector(l_, h_, 0, 1, 2, 3, 4, 5, 6, 7)

  const int aoff = wr * 4 * 2048;           // A frag base within a buf (sb = wr*4+m)
  const int boff = 16384 + wc * 4 * 2048;   // B frag base within a buf (sb = wc*4+n)

  f32x16 acc[4][4] = {};
  i32x4 aEl[4], aEh[4], bEl[4], bEh[4];     // frag halves, even tiles
  i32x4 aOl[4], aOh[4], bOl[4], bOh[4];     // frag halves, odd tiles

  // ---- Prologue: stage tile 0 -> buf0, tile 1 -> buf1; read E = tile 0.
  STAGE_TILE(0, 0);
  __builtin_amdgcn_sched_barrier(0);
  STAGE_TILE(16384, 32768);
  __builtin_amdgcn_sched_barrier(0);
  asm volatile("s_waitcnt vmcnt(8)" ::: "memory");   // tile 0 landed (this wave)
  __builtin_amdgcn_s_barrier();                      // ...all waves
  #pragma unroll
  for (int m = 0; m < 4; ++m) RD(aEl[m], aEh[m], aoff + m * 2048);
  #pragma unroll
  for (int n = 0; n < 4; ++n) RD(bEl[n], bEh[n], boff + n * 2048);
  asm volatile("s_waitcnt lgkmcnt(0)" ::: "memory");
  __builtin_amdgcn_sched_barrier(0);
  __builtin_amdgcn_s_barrier();                      // buf0 free for restage

#define CLUSTER(al, ah, bl, bh)                                             \
  {                                                                         \
    __builtin_amdgcn_s_setprio(1);                                          \
    i32x8 B0 = J(bl[0], bh[0]), B1 = J(bl[1], bh[1]),                       \
          B2 = J(bl[2], bh[2]), B3 = J(bl[3], bh[3]);                       \
    _Pragma("unroll")                                                       \
    for (int m = 0; m < 4; ++m) {                                           \
      i32x8 Am = J(al[m], ah[m]);                                           \
      acc[m][0] = __builtin_amdgcn_mfma_scale_f32_32x32x64_f8f6f4(          \
          Am, B0, acc[m][0], 1, 0, 0, 0x7F7F7F7F, 0, 0x7F7F7F7F);           \
      acc[m][1] = __builtin_amdgcn_mfma_scale_f32_32x32x64_f8f6f4(          \
          Am, B1, acc[m][1], 1, 0, 0, 0x7F7F7F7F, 0, 0x7F7F7F7F);           \
      acc[m][2] = __builtin_amdgcn_mfma_scale_f32_32x32x64_f8f6f4(          \
          Am, B2, acc[m][2], 1, 0, 0, 0x7F7F7F7F, 0, 0x7F7F7F7F);           \
      acc[m][3] = __builtin_amdgcn_mfma_scale_f32_32x32x64_f8f6f4(          \
          Am, B3, acc[m][3], 1, 0, 0, 0x7F7F7F7F, 0, 0x7F7F7F7F);           \
    }                                                                       \
    __builtin_amdgcn_s_setprio(0);                                          \
  }

  for (int kt = 0; kt < 64; kt += 2) {
    // ===== EVEN: compute tile kt (E); stage kt+2 -> buf0; read kt+1 -> O.
    {
      const size_t tp = (size_t)((kt + 2) & 63) * 16384;
      STAGE_TILE(tp, 0);
      asm volatile("s_waitcnt vmcnt(8)" ::: "memory");   // tile kt+1 landed
      __builtin_amdgcn_s_barrier();                      // ...on all waves
      #pragma unroll
      for (int m = 0; m < 4; ++m) RD(aOl[m], aOh[m], 32768 + aoff + m * 2048);
      #pragma unroll
      for (int n = 0; n < 4; ++n) RD(bOl[n], bOh[n], 32768 + boff + n * 2048);
      __builtin_amdgcn_sched_barrier(0);                 // reads issue BEFORE cluster
      CLUSTER(aEl, aEh, bEl, bEh);
      __builtin_amdgcn_sched_barrier(0);
      asm volatile("s_waitcnt lgkmcnt(0)" ::: "memory"); // O frag reads done
      __builtin_amdgcn_sched_barrier(0);
      __builtin_amdgcn_s_barrier();                      // buf1 free for restage
    }
    // ===== ODD: compute tile kt+1 (O); stage kt+3 -> buf1; read kt+2 -> E.
    {
      const size_t tp = (size_t)((kt + 3) & 63) * 16384;
      STAGE_TILE(tp, 32768);
      asm volatile("s_waitcnt vmcnt(8)" ::: "memory");   // tile kt+2 landed
      __builtin_amdgcn_s_barrier();
      #pragma unroll
      for (int m = 0; m < 4; ++m) RD(aEl[m], aEh[m], aoff + m * 2048);
      #pragma unroll
      for (int n = 0; n < 4; ++n) RD(bEl[n], bEh[n], boff + n * 2048);
      __builtin_amdgcn_sched_barrier(0);
      CLUSTER(aOl, aOh, bOl, bOh);
      __builtin_amdgcn_sched_barrier(0);
      asm volatile("s_waitcnt lgkmcnt(0)" ::: "memory");
      __builtin_amdgcn_sched_barrier(0);
      __builtin_amdgcn_s_barrier();                      // buf0 free for restage
    }
  }
#undef STAGE
#undef STAGE_TILE
#undef RD
#undef J
#undef CLUSTER

  // Epilogue: +bias, round through fp16 (matches reference), store f32.
  // 32x32 C/D layout: col = lane&31, row = (r&3) + 8*(r>>2) + 4*(lane>>5).
  #pragma unroll
  for (int n = 0; n < 4; ++n) {
    const int col = bni * 256 + wc * 128 + n * 32 + (lane & 31);
    const float bv = bias[col];
    #pragma unroll
    for (int m = 0; m < 4; ++m) {
      const int rbase = bmi * 256 + wr * 128 + m * 32 + ((lane >> 5) << 2);
      #pragma unroll
      for (int r = 0; r < 16; ++r) {
        const int row = rbase + (r & 3) + 8 * (r >> 2);
        C[(size_t)row * N_DIM + col] =
            __half2float(__float2half_rn(acc[m][n][r] + bv));
      }
    }
  }
}

// ---------------------------------------------------------------------------
extern "C" void kernel_launch(void* const* d_in, const int* in_sizes, int n_in,
                              void* d_out, int out_size, void* d_ws, size_t ws_size,
                              hipStream_t stream) {
  const float* x  = (const float*)d_in[0];   // [B,S,DIN] fp16-exact values in f32
  const float* w  = (const float*)d_in[1];   // [DOUT,DIN]
  const float* bs = (const float*)d_in[2];   // [DOUT]
  float* out = (float*)d_out;

  // Workspace: xq = 64 MiB e5m2 (tiled), wq = 16 MiB e4m3 (tiled)
  unsigned char* xq = (unsigned char*)d_ws;
  unsigned char* wq = (unsigned char*)d_ws + (size_t)M_DIM * K_DIM;

  const int ngx = (M_DIM * K_DIM) / 16;   // 4,194,304 groups
  const int ngw = (N_DIM * K_DIM) / 16;   // 1,048,576 groups
  quant_tile_kernel<false><<<ngx / 256, 256, 0, stream>>>(x, (uint4*)xq, ngx);
  quant_tile_kernel<true ><<<ngw / 256, 256, 0, stream>>>(w, (uint4*)wq, ngw);

  gemm_fp8_kernel<<<1024, 256, 0, stream>>>(xq, wq, bs, out);
}

// Round 7
// 409.733 us; speedup vs baseline: 2.6098x; 2.6098x over previous
//
#include <hip/hip_runtime.h>
#include <hip/hip_fp16.h>

// Problem constants (fixed by the reference file)
#define M_DIM 16384   // B*S = 4*4096
#define N_DIM 4096    // DOUT
#define K_DIM 4096    // DIN

typedef __attribute__((ext_vector_type(16))) float f32x16;
typedef __attribute__((ext_vector_type(4)))  int   i32x4;
typedef __attribute__((ext_vector_type(8)))  int   i32x8;

// ---------------------------------------------------------------------------
// Quantize fp32 (fp16-exact values) -> fp8 RNE, emitting the 32x32x64 MFMA
// fragment-order tiled layout for 256-row blocks (UNCHANGED, verified r3-r6):
//   out = [nrow/256][K/64] tiles of 16384 B.
//   tile byte p = sb*2048 + half*1024 + l*16 + b   (sb 0..7, half 0..1,
//   l 0..63, b 0..15) holds element
//     row = tile_r*256 + sb*32 + (l&31)
//     k   = tile_k*64  + (l>>5)*32 + half*16 + b
//   so GEMM lane l reads its v_mfma_f32_32x32x64_f8f6f4 fragment as two
//   contiguous ds_read_b128 (base, base+1024) -> 0 bank conflicts; staging
//   is linear (global_load_lds-compatible).
// E4M3=true -> OCP e4m3fn (weight); false -> OCP e5m2 (activations).
// ---------------------------------------------------------------------------
template<bool E4M3>
__global__ __launch_bounds__(256) void quant_tile_kernel(
    const float* __restrict__ in,   // [R, K_DIM] row-major f32
    uint4* __restrict__ out,        // tiled fp8 bytes, R*K_DIM/16 groups
    int ngrp)
{
  int t = blockIdx.x * 256 + threadIdx.x;
  if (t >= ngrp) return;
  const int g    = t & 1023;        // 16-byte group within 16 KiB tile
  const int tile = t >> 10;
  const int kt   = tile & 63;       // K/64 = 64 K-tiles
  const int bt   = tile >> 6;       // 256-row block
  const int sb   = g >> 7;          // 32-row sub-block (0..7)
  const int half = (g >> 6) & 1;
  const int l    = g & 63;
  const int row  = bt * 256 + sb * 32 + (l & 31);
  const int k    = kt * 64 + (l >> 5) * 32 + half * 16;

  const float4* p = reinterpret_cast<const float4*>(in + (size_t)row * K_DIM + k);
  float4 v0 = p[0], v1 = p[1], v2 = p[2], v3 = p[3];
  int w0 = 0, w1 = 0, w2 = 0, w3 = 0;
  if (E4M3) {
    w0 = __builtin_amdgcn_cvt_pk_fp8_f32(v0.x, v0.y, w0, false);
    w0 = __builtin_amdgcn_cvt_pk_fp8_f32(v0.z, v0.w, w0, true);
    w1 = __builtin_amdgcn_cvt_pk_fp8_f32(v1.x, v1.y, w1, false);
    w1 = __builtin_amdgcn_cvt_pk_fp8_f32(v1.z, v1.w, w1, true);
    w2 = __builtin_amdgcn_cvt_pk_fp8_f32(v2.x, v2.y, w2, false);
    w2 = __builtin_amdgcn_cvt_pk_fp8_f32(v2.z, v2.w, w2, true);
    w3 = __builtin_amdgcn_cvt_pk_fp8_f32(v3.x, v3.y, w3, false);
    w3 = __builtin_amdgcn_cvt_pk_fp8_f32(v3.z, v3.w, w3, true);
  } else {
    w0 = __builtin_amdgcn_cvt_pk_bf8_f32(v0.x, v0.y, w0, false);
    w0 = __builtin_amdgcn_cvt_pk_bf8_f32(v0.z, v0.w, w0, true);
    w1 = __builtin_amdgcn_cvt_pk_bf8_f32(v1.x, v1.y, w1, false);
    w1 = __builtin_amdgcn_cvt_pk_bf8_f32(v1.z, v1.w, w1, true);
    w2 = __builtin_amdgcn_cvt_pk_bf8_f32(v2.x, v2.y, w2, false);
    w2 = __builtin_amdgcn_cvt_pk_bf8_f32(v2.z, v2.w, w2, true);
    w3 = __builtin_amdgcn_cvt_pk_bf8_f32(v3.x, v3.y, w3, false);
    w3 = __builtin_amdgcn_cvt_pk_bf8_f32(v3.z, v3.w, w3, true);
  }
  out[t] = make_uint4((unsigned)w0, (unsigned)w1, (unsigned)w2, (unsigned)w3);
}

// ---------------------------------------------------------------------------
// MX-fp8 GEMM, fat-wave regime, SINGLE frag set (round-6 spill fix):
// 256x256 block tile, BK=64, 4 waves (2Mx2N), per-wave 128x128 output =
// acc[4][4] f32x16 (256 regs -> AGPRs) at 1 wave/SIMD; live VGPR ~100.
// Per window (1 K-tile): issue 16 ds_read_b128 (B0-3 then A0-3); counted
// lgkmcnt(6/4/2/0) gates MFMA rows so the last 6 reads hide under rows 0-2;
// barrier; stage kt+2 into the just-freed buffer; vmcnt(8) (tile kt+1
// landed); barrier. vmcnt never drained to 0 in the loop.
// FLOP/LDS-byte = 128 (vs 85 for the 8-wave 128x64 variant): LDS traffic
// 64 KB/CU/window vs 96 KB.
// ---------------------------------------------------------------------------
__global__ __launch_bounds__(256, 1) void gemm_fp8_kernel(
    const unsigned char* __restrict__ Aq,   // tiled [64][64][16384] e5m2
    const unsigned char* __restrict__ Wq,   // tiled [16][64][16384] e4m3
    const float* __restrict__ bias,         // [N] fp16-exact values in f32
    float* __restrict__ C)                  // [M,N] f32 (fp16-rounded values)
{
  __shared__ __align__(16) unsigned char lds[65536];  // buf0|buf1, each {A 16K, B 16K}

  const int tid  = threadIdx.x;
  const int lane = tid & 63;
  const int wave = tid >> 6;                // 0..3
  const int wr   = wave >> 1;               // 0..1 -> 128 rows
  const int wc   = wave & 1;                // 0..1 -> 128 cols

  // T1: XCD swizzle (nwg=1024, %8==0). XCD x gets bni in {2x,2x+1}:
  // B panels (2 MB) L2-resident per XCD; A panels stream through LLC.
  const int bid = blockIdx.x;
  const int swz = (bid & 7) * 128 + (bid >> 3);
  const int bni = swz >> 6;                 // 0..15
  const int bmi = swz & 63;                 // 0..63

  const unsigned char* tA = Aq + (size_t)bmi * (64 * 16384);
  const unsigned char* tB = Wq + (size_t)bni * (64 * 16384);

  const size_t t16 = (size_t)tid * 16;      // per-lane global offset
  const int    w1k = wave * 1024;           // wave-uniform LDS offset

#define STAGE(gb, lo_)                                                      \
  __builtin_amdgcn_global_load_lds(                                        \
      (const __attribute__((address_space(1))) void*)((gb) + t16),          \
      (__attribute__((address_space(3))) void*)(lds + (lo_) + w1k), 16, 0, 0)

  // Stage one K-tile (A 16 KiB + B 16 KiB): 8 loads x 256 thr x 16 B.
#define STAGE_TILE(tp, ldsbase)                                             \
  STAGE(tA + (tp),         (ldsbase) + 0);                                  \
  STAGE(tA + (tp) + 4096,  (ldsbase) + 4096);                               \
  STAGE(tA + (tp) + 8192,  (ldsbase) + 8192);                               \
  STAGE(tA + (tp) + 12288, (ldsbase) + 12288);                              \
  STAGE(tB + (tp),         (ldsbase) + 16384);                              \
  STAGE(tB + (tp) + 4096,  (ldsbase) + 20480);                              \
  STAGE(tB + (tp) + 8192,  (ldsbase) + 24576);                              \
  STAGE(tB + (tp) + 12288, (ldsbase) + 28672)

  // One fragment = two contiguous ds_read_b128 landing in one i32x8's
  // register pair (no join movs).
#define RD8(dst, off)                                                       \
  { const unsigned char* _p = lds + (off) + lane * 16;                      \
    union { i32x8 v; i32x4 h[2]; } _u;                                      \
    _u.h[0] = *(const i32x4*)_p;                                            \
    _u.h[1] = *(const i32x4*)(_p + 1024);                                   \
    (dst) = _u.v; }

#define MFMA(d, a, b)                                                       \
  d = __builtin_amdgcn_mfma_scale_f32_32x32x64_f8f6f4(                      \
      a, b, d, 1 /*A=e5m2*/, 0 /*B=e4m3*/, 0, 0x7F7F7F7F, 0, 0x7F7F7F7F)

#define SB __builtin_amdgcn_sched_barrier(0)

  const int aoff = wr * 8192;               // A frag base within a buf
  const int boff = 16384 + wc * 8192;       // B frag base within a buf

  f32x16 acc[4][4] = {};

  // ---- Prologue: stage tile 0 -> buf0, tile 1 -> buf1.
  STAGE_TILE(0, 0);
  SB;
  STAGE_TILE(16384, 32768);
  SB;
  asm volatile("s_waitcnt vmcnt(8)" ::: "memory");   // tile 0 landed (this wave)
  SB;
  __builtin_amdgcn_s_barrier();                      // ...all waves

  for (int kt = 0; kt < 64; ++kt) {
    const int bufo = (kt & 1) * 32768;
    const size_t tp = (size_t)((kt + 2) & 63) * 16384;

    i32x8 b0, b1, b2, b3, a0, a1, a2, a3;
    // Issue order matters for the counted lgkm waits: B0-3 (8 rds), A0-3 (8).
    RD8(b0, bufo + boff + 0 * 2048);
    RD8(b1, bufo + boff + 1 * 2048);
    RD8(b2, bufo + boff + 2 * 2048);
    RD8(b3, bufo + boff + 3 * 2048);
    RD8(a0, bufo + aoff + 0 * 2048);
    RD8(a1, bufo + aoff + 1 * 2048);
    RD8(a2, bufo + aoff + 2 * 2048);
    RD8(a3, bufo + aoff + 3 * 2048);
    SB;
    asm volatile("s_waitcnt lgkmcnt(6)" ::: "memory");   // B0-3 + A0 done
    SB;
    MFMA(acc[0][0], a0, b0); MFMA(acc[0][1], a0, b1);
    MFMA(acc[0][2], a0, b2); MFMA(acc[0][3], a0, b3);
    SB;
    asm volatile("s_waitcnt lgkmcnt(4)" ::: "memory");   // + A1
    SB;
    MFMA(acc[1][0], a1, b0); MFMA(acc[1][1], a1, b1);
    MFMA(acc[1][2], a1, b2); MFMA(acc[1][3], a1, b3);
    SB;
    asm volatile("s_waitcnt lgkmcnt(2)" ::: "memory");   // + A2
    SB;
    MFMA(acc[2][0], a2, b0); MFMA(acc[2][1], a2, b1);
    MFMA(acc[2][2], a2, b2); MFMA(acc[2][3], a2, b3);
    SB;
    asm volatile("s_waitcnt lgkmcnt(0)" ::: "memory");   // + A3
    SB;
    MFMA(acc[3][0], a3, b0); MFMA(acc[3][1], a3, b1);
    MFMA(acc[3][2], a3, b2); MFMA(acc[3][3], a3, b3);
    SB;
    __builtin_amdgcn_s_barrier();            // all waves done reading buf[cur]
    STAGE_TILE(tp, bufo);                    // refill just-freed buffer
    SB;
    asm volatile("s_waitcnt vmcnt(8)" ::: "memory");     // tile kt+1 landed
    SB;
    __builtin_amdgcn_s_barrier();            // ...visible to all waves
  }
#undef STAGE
#undef STAGE_TILE
#undef RD8
#undef MFMA
#undef SB

  // Epilogue: +bias, round through fp16 (matches reference), store f32.
  // 32x32 C/D layout: col = lane&31, row = (r&3) + 8*(r>>2) + 4*(lane>>5).
  // (Verified in round 6 — unchanged.)
  #pragma unroll
  for (int n = 0; n < 4; ++n) {
    const int col = bni * 256 + wc * 128 + n * 32 + (lane & 31);
    const float bv = bias[col];
    #pragma unroll
    for (int m = 0; m < 4; ++m) {
      const int rbase = bmi * 256 + wr * 128 + m * 32 + ((lane >> 5) << 2);
      #pragma unroll
      for (int r = 0; r < 16; ++r) {
        const int row = rbase + (r & 3) + 8 * (r >> 2);
        C[(size_t)row * N_DIM + col] =
            __half2float(__float2half_rn(acc[m][n][r] + bv));
      }
    }
  }
}

// ---------------------------------------------------------------------------
extern "C" void kernel_launch(void* const* d_in, const int* in_sizes, int n_in,
                              void* d_out, int out_size, void* d_ws, size_t ws_size,
                              hipStream_t stream) {
  const float* x  = (const float*)d_in[0];   // [B,S,DIN] fp16-exact values in f32
  const float* w  = (const float*)d_in[1];   // [DOUT,DIN]
  const float* bs = (const float*)d_in[2];   // [DOUT]
  float* out = (float*)d_out;

  // Workspace: xq = 64 MiB e5m2 (tiled), wq = 16 MiB e4m3 (tiled)
  unsigned char* xq = (unsigned char*)d_ws;
  unsigned char* wq = (unsigned char*)d_ws + (size_t)M_DIM * K_DIM;

  const int ngx = (M_DIM * K_DIM) / 16;   // 4,194,304 groups
  const int ngw = (N_DIM * K_DIM) / 16;   // 1,048,576 groups
  quant_tile_kernel<false><<<ngx / 256, 256, 0, stream>>>(x, (uint4*)xq, ngx);
  quant_tile_kernel<true ><<<ngw / 256, 256, 0, stream>>>(w, (uint4*)wq, ngw);

  gemm_fp8_kernel<<<1024, 256, 0, stream>>>(xq, wq, bs, out);
}

// Round 8
// 353.674 us; speedup vs baseline: 3.0234x; 1.1585x over previous
//
#include <hip/hip_runtime.h>
#include <hip/hip_fp16.h>

// Problem constants (fixed by the reference file)
#define M_DIM 16384   // B*S = 4*4096
#define N_DIM 4096    // DOUT
#define K_DIM 4096    // DIN

typedef __attribute__((ext_vector_type(16))) float f32x16;
typedef __attribute__((ext_vector_type(4)))  int   i32x4;
typedef __attribute__((ext_vector_type(8)))  int   i32x8;

// ---------------------------------------------------------------------------
// Quantize fp32 (fp16-exact values) -> fp8 RNE, emitting the 32x32x64 MFMA
// fragment-order tiled layout for 256-row blocks (UNCHANGED, verified r3-r7):
//   out = [nrow/256][K/64] tiles of 16384 B.
//   tile byte p = sb*2048 + half*1024 + l*16 + b   (sb 0..7, half 0..1,
//   l 0..63, b 0..15) holds element
//     row = tile_r*256 + sb*32 + (l&31)
//     k   = tile_k*64  + (l>>5)*32 + half*16 + b
//   so GEMM lane l reads its v_mfma_f32_32x32x64_f8f6f4 fragment as two
//   contiguous ds_read_b128 (base, base+1024) -> 0 bank conflicts; staging
//   is linear (global_load_lds-compatible).
// E4M3=true -> OCP e4m3fn (weight); false -> OCP e5m2 (activations).
// ---------------------------------------------------------------------------
template<bool E4M3>
__global__ __launch_bounds__(256) void quant_tile_kernel(
    const float* __restrict__ in,   // [R, K_DIM] row-major f32
    uint4* __restrict__ out,        // tiled fp8 bytes, R*K_DIM/16 groups
    int ngrp)
{
  int t = blockIdx.x * 256 + threadIdx.x;
  if (t >= ngrp) return;
  const int g    = t & 1023;        // 16-byte group within 16 KiB tile
  const int tile = t >> 10;
  const int kt   = tile & 63;       // K/64 = 64 K-tiles
  const int bt   = tile >> 6;       // 256-row block
  const int sb   = g >> 7;          // 32-row sub-block (0..7)
  const int half = (g >> 6) & 1;
  const int l    = g & 63;
  const int row  = bt * 256 + sb * 32 + (l & 31);
  const int k    = kt * 64 + (l >> 5) * 32 + half * 16;

  const float4* p = reinterpret_cast<const float4*>(in + (size_t)row * K_DIM + k);
  float4 v0 = p[0], v1 = p[1], v2 = p[2], v3 = p[3];
  int w0 = 0, w1 = 0, w2 = 0, w3 = 0;
  if (E4M3) {
    w0 = __builtin_amdgcn_cvt_pk_fp8_f32(v0.x, v0.y, w0, false);
    w0 = __builtin_amdgcn_cvt_pk_fp8_f32(v0.z, v0.w, w0, true);
    w1 = __builtin_amdgcn_cvt_pk_fp8_f32(v1.x, v1.y, w1, false);
    w1 = __builtin_amdgcn_cvt_pk_fp8_f32(v1.z, v1.w, w1, true);
    w2 = __builtin_amdgcn_cvt_pk_fp8_f32(v2.x, v2.y, w2, false);
    w2 = __builtin_amdgcn_cvt_pk_fp8_f32(v2.z, v2.w, w2, true);
    w3 = __builtin_amdgcn_cvt_pk_fp8_f32(v3.x, v3.y, w3, false);
    w3 = __builtin_amdgcn_cvt_pk_fp8_f32(v3.z, v3.w, w3, true);
  } else {
    w0 = __builtin_amdgcn_cvt_pk_bf8_f32(v0.x, v0.y, w0, false);
    w0 = __builtin_amdgcn_cvt_pk_bf8_f32(v0.z, v0.w, w0, true);
    w1 = __builtin_amdgcn_cvt_pk_bf8_f32(v1.x, v1.y, w1, false);
    w1 = __builtin_amdgcn_cvt_pk_bf8_f32(v1.z, v1.w, w1, true);
    w2 = __builtin_amdgcn_cvt_pk_bf8_f32(v2.x, v2.y, w2, false);
    w2 = __builtin_amdgcn_cvt_pk_bf8_f32(v2.z, v2.w, w2, true);
    w3 = __builtin_amdgcn_cvt_pk_bf8_f32(v3.x, v3.y, w3, false);
    w3 = __builtin_amdgcn_cvt_pk_bf8_f32(v3.z, v3.w, w3, true);
  }
  out[t] = make_uint4((unsigned)w0, (unsigned)w1, (unsigned)w2, (unsigned)w3);
}

// ---------------------------------------------------------------------------
// MX-fp8 GEMM — 8-phase schedule (m201 template port): 256x256 block tile,
// BK=64, 8 waves (2M x 4N), per-wave 128x64 = acc[4][2] f32x16, 2 waves/SIMD.
// LDS: TRIPLE buffer 3 x {A 16K | B 16K} = 96 KiB. Tile t lives in buf[t%3];
// tile t+2 is staged piece-per-phase into buf[(t+2)%3], which was fully
// consumed at the end of tile t-1 (trailing barrier) -> no region hazards.
// Phase = {ds_read frags, 1 gload_lds piece, barrier, lgkmcnt(0)+schedbar,
// setprio(1), 2 MFMA, setprio(0), barrier}. vmcnt(4) only at phases 4 & 8.
// ---------------------------------------------------------------------------
__global__ __launch_bounds__(512, 2) void gemm_fp8_kernel(
    const unsigned char* __restrict__ Aq,   // tiled [64][64][16384] e5m2
    const unsigned char* __restrict__ Wq,   // tiled [16][64][16384] e4m3
    const float* __restrict__ bias,         // [N] fp16-exact values in f32
    float* __restrict__ C)                  // [M,N] f32 (fp16-rounded values)
{
  __shared__ __align__(16) unsigned char lds[98304];  // 3 bufs x {A 16K, B 16K}

  const int tid  = threadIdx.x;
  const int lane = tid & 63;
  const int wave = tid >> 6;                // 0..7
  const int wr   = wave >> 2;               // 0..1 -> 128 rows
  const int wc   = wave & 3;                // 0..3 -> 64 cols

  // T1: XCD swizzle, r4 mapping (measured FETCH 304 MB vs 565 for the flip).
  const int bid = blockIdx.x;
  const int swz = (bid & 7) * 128 + (bid >> 3);
  const int bmi = swz >> 4;                 // 0..63
  const int bni = swz & 15;                 // 0..15

  const unsigned char* tA = Aq + (size_t)bmi * (64 * 16384);
  const unsigned char* tB = Wq + (size_t)bni * (64 * 16384);

  const size_t t16 = (size_t)tid * 16;      // per-lane global offset (0..8176)
  const int    w1k = wave * 1024;           // wave-uniform LDS sub-offset

  // Stage one 8 KiB piece: 512 thr x 16 B. dst = wave-uniform base (+lane*16 hw).
#define STAGE(gb, lo_)                                                      \
  __builtin_amdgcn_global_load_lds(                                        \
      (const __attribute__((address_space(1))) void*)((gb) + t16),          \
      (__attribute__((address_space(3))) void*)(lds + (lo_) + w1k), 16, 0, 0)

  // One fragment = two contiguous ds_read_b128 into one i32x8 (no join movs).
#define RD8(dst, off)                                                       \
  { const unsigned char* _p = lds + (off) + lane * 16;                      \
    union { i32x8 v; i32x4 h[2]; } _u;                                      \
    _u.h[0] = *(const i32x4*)_p;                                            \
    _u.h[1] = *(const i32x4*)(_p + 1024);                                   \
    (dst) = _u.v; }

#define MFMA(d, a, b)                                                       \
  d = __builtin_amdgcn_mfma_scale_f32_32x32x64_f8f6f4(                      \
      a, b, d, 1 /*A=e5m2*/, 0 /*B=e4m3*/, 0, 0x7F7F7F7F, 0, 0x7F7F7F7F)

#define SBAR __builtin_amdgcn_sched_barrier(0)
#define BAR  __builtin_amdgcn_s_barrier()
#define DSW  asm volatile("s_waitcnt lgkmcnt(0)" ::: "memory"); SBAR
#define VMW4 asm volatile("s_waitcnt vmcnt(4)" ::: "memory"); SBAR
#define P1   __builtin_amdgcn_s_setprio(1)
#define P0   __builtin_amdgcn_s_setprio(0)

  const int aoff = wr * 8192;               // A frag base within a buf
  const int boff = 16384 + wc * 4096;       // B frag base within a buf

  f32x16 acc[4][2] = {};
  i32x8 aU, aV, bE0, bE1, bO0, bO1;

  // ---- Prologue: stage tile 0 -> buf0, tile 1 -> buf1 (4 pieces each).
  STAGE(tA,         0);      STAGE(tA + 8192,  8192);
  STAGE(tB,         16384);  STAGE(tB + 8192,  24576);
  SBAR;
  STAGE(tA + 16384, 32768);  STAGE(tA + 24576, 40960);
  STAGE(tB + 16384, 49152);  STAGE(tB + 24576, 57344);
  SBAR;
  VMW4;                                     // tile 0 landed (own segments)
  BAR;                                      // ...all waves' segments

  int cA = 0, cB = 32768, cC = 65536;       // bufs of tiles t, t+1, t+2

  for (int it = 0; it < 32; ++it) {
    const int t = it << 1;
    const size_t tpC = (size_t)((t + 2) & 63) * 16384;
    const size_t tpD = (size_t)((t + 3) & 63) * 16384;

    // ===== Tile t (even) — buf cA; stage tile t+2 -> buf cC =====
    // Ph0
    RD8(bE0, cA + boff);  RD8(bE1, cA + boff + 2048);
    RD8(aU,  cA + aoff);
    STAGE(tA + tpC, cC);
    BAR; DSW; P1;
    MFMA(acc[0][0], aU, bE0); MFMA(acc[0][1], aU, bE1);
    P0; BAR;
    // Ph1
    RD8(aV, cA + aoff + 2048);
    STAGE(tA + tpC + 8192, cC + 8192);
    BAR; DSW; P1;
    MFMA(acc[1][0], aV, bE0); MFMA(acc[1][1], aV, bE1);
    P0; BAR;
    // Ph2
    RD8(aU, cA + aoff + 4096);
    STAGE(tB + tpC, cC + 16384);
    BAR; DSW; P1;
    MFMA(acc[2][0], aU, bE0); MFMA(acc[2][1], aU, bE1);
    P0; BAR;
    // Ph3
    RD8(aV, cA + aoff + 6144);
    STAGE(tB + tpC + 8192, cC + 24576);
    BAR; DSW; P1;
    MFMA(acc[3][0], aV, bE0); MFMA(acc[3][1], aV, bE1);
    P0;
    VMW4;                                   // tile t+1 landed
    BAR;

    // ===== Tile t+1 (odd) — buf cB; stage tile t+3 -> buf cA =====
    // Ph4
    RD8(bO0, cB + boff);  RD8(bO1, cB + boff + 2048);
    RD8(aU,  cB + aoff);
    STAGE(tA + tpD, cA);
    BAR; DSW; P1;
    MFMA(acc[0][0], aU, bO0); MFMA(acc[0][1], aU, bO1);
    P0; BAR;
    // Ph5
    RD8(aV, cB + aoff + 2048);
    STAGE(tA + tpD + 8192, cA + 8192);
    BAR; DSW; P1;
    MFMA(acc[1][0], aV, bO0); MFMA(acc[1][1], aV, bO1);
    P0; BAR;
    // Ph6
    RD8(aU, cB + aoff + 4096);
    STAGE(tB + tpD, cA + 16384);
    BAR; DSW; P1;
    MFMA(acc[2][0], aU, bO0); MFMA(acc[2][1], aU, bO1);
    P0; BAR;
    // Ph7
    RD8(aV, cB + aoff + 6144);
    STAGE(tB + tpD + 8192, cA + 24576);
    BAR; DSW; P1;
    MFMA(acc[3][0], aV, bO0); MFMA(acc[3][1], aV, bO1);
    P0;
    VMW4;                                   // tile t+2 landed
    BAR;

    // Rotate buffers: next tiles (t+2, t+3, t+4) -> (cC, cA, cB).
    const int nA = cC, nB = cA, nC = cB;
    cA = nA; cB = nB; cC = nC;
  }
#undef STAGE
#undef RD8
#undef MFMA
#undef SBAR
#undef BAR
#undef DSW
#undef VMW4
#undef P1
#undef P0

  // Epilogue: +bias, round through fp16 (matches reference), store f32.
  // 32x32 C/D layout (verified r3-r7): col = lane&31,
  // row = (r&3) + 8*(r>>2) + 4*(lane>>5).
  #pragma unroll
  for (int n = 0; n < 2; ++n) {
    const int col = bni * 256 + wc * 64 + n * 32 + (lane & 31);
    const float bv = bias[col];
    #pragma unroll
    for (int m = 0; m < 4; ++m) {
      const int rbase = bmi * 256 + wr * 128 + m * 32 + ((lane >> 5) << 2);
      #pragma unroll
      for (int r = 0; r < 16; ++r) {
        const int row = rbase + (r & 3) + 8 * (r >> 2);
        C[(size_t)row * N_DIM + col] =
            __half2float(__float2half_rn(acc[m][n][r] + bv));
      }
    }
  }
}

// ---------------------------------------------------------------------------
extern "C" void kernel_launch(void* const* d_in, const int* in_sizes, int n_in,
                              void* d_out, int out_size, void* d_ws, size_t ws_size,
                              hipStream_t stream) {
  const float* x  = (const float*)d_in[0];   // [B,S,DIN] fp16-exact values in f32
  const float* w  = (const float*)d_in[1];   // [DOUT,DIN]
  const float* bs = (const float*)d_in[2];   // [DOUT]
  float* out = (float*)d_out;

  // Workspace: xq = 64 MiB e5m2 (tiled), wq = 16 MiB e4m3 (tiled)
  unsigned char* xq = (unsigned char*)d_ws;
  unsigned char* wq = (unsigned char*)d_ws + (size_t)M_DIM * K_DIM;

  const int ngx = (M_DIM * K_DIM) / 16;   // 4,194,304 groups
  const int ngw = (N_DIM * K_DIM) / 16;   // 1,048,576 groups
  quant_tile_kernel<false><<<ngx / 256, 256, 0, stream>>>(x, (uint4*)xq, ngx);
  quant_tile_kernel<true ><<<ngw / 256, 256, 0, stream>>>(w, (uint4*)wq, ngw);

  gemm_fp8_kernel<<<1024, 512, 0, stream>>>(xq, wq, bs, out);
}